// Round 1
// baseline (259.983 us; speedup 1.0000x reference)
//
#include <hip/hip_runtime.h>

#define S_DIM 128
#define A_DIM 96
#define B_DIM 256
#define LX 512
#define LY 256

// Kernel A: C[x][y] = 1 - softmax(P, axis=1)[x][y].  One wave per row of P.
__global__ __launch_bounds__(64) void softmax_kernel(const float* __restrict__ P,
                                                     float* __restrict__ C) {
    int row = blockIdx.x;      // 0..S_DIM-1
    int lane = threadIdx.x;    // 0..63
    const float* p = P + row * A_DIM;
    float v0 = p[lane];
    float v1 = (lane < A_DIM - 64) ? p[64 + lane] : -1e30f;
    float m = fmaxf(v0, v1);
    #pragma unroll
    for (int d = 32; d > 0; d >>= 1) m = fmaxf(m, __shfl_xor(m, d));
    float e0 = expf(v0 - m);
    float e1 = (lane < A_DIM - 64) ? expf(v1 - m) : 0.0f;
    float s = e0 + e1;
    #pragma unroll
    for (int d = 32; d > 0; d >>= 1) s += __shfl_xor(s, d);
    float inv = 1.0f / s;
    C[row * A_DIM + lane] = 1.0f - e0 * inv;
    if (lane < A_DIM - 64) C[row * A_DIM + 64 + lane] = 1.0f - e1 * inv;
}

// Kernel B: one wave (64 lanes) per batch element. Lane l owns columns
// j = 4l+1 .. 4l+4 of the DP row (j=0 is analytically D[i][0]=i).
__global__ __launch_bounds__(64) void dp_kernel(const float* __restrict__ C,
                                                const int* __restrict__ xs,
                                                const int* __restrict__ ys,
                                                const int* __restrict__ xlen,
                                                const int* __restrict__ ylen,
                                                float* __restrict__ out) {
    int b = blockIdx.x;
    int lane = threadIdx.x;
    int xl = xlen[b] - 1;      // rows to compute: i = 1..xl   (xl in [1, LX-1])
    int yl = ylen[b] - 1;      // output column                (yl in [1, LY-1])

    const int* ysb = ys + b * LY;
    int4 yv = *reinterpret_cast<const int4*>(ysb + lane * 4);
    int y0 = yv.x, y1 = yv.y, y2 = yv.z, y3 = yv.w;
    const int* xsb = xs + b * LX;

    // Row 0: D0[j] = j
    float j0 = (float)(4 * lane + 1);
    float d0 = j0, d1 = j0 + 1.0f, d2 = j0 + 2.0f, d3 = j0 + 3.0f;

    // Prefetch row 1 costs
    int x = xsb[0];
    const float* Crow = C + x * A_DIM;
    float c0 = Crow[y0], c1 = Crow[y1], c2 = Crow[y2], c3 = Crow[y3];

    for (int i = 1; i <= xl; ++i) {
        float cc0 = c0, cc1 = c1, cc2 = c2, cc3 = c3;
        if (i < xl) {   // prefetch next row's costs (hides L1/L2 latency)
            int xn = xsb[i];
            const float* Cn = C + xn * A_DIM;
            c0 = Cn[y0]; c1 = Cn[y1]; c2 = Cn[y2]; c3 = Cn[y3];
        }
        float im1 = (float)(i - 1);

        // E_full[j] = min(Dprev[j]+1, Dprev[j-1]+c[j-1]); left neighbor via shuffle
        float left = __shfl_up(d3, 1);
        if (lane == 0) left = im1;         // Dprev[0] = i-1
        float E0 = fminf(d0 + 1.0f, left + cc0);
        float E1 = fminf(d1 + 1.0f, d0 + cc1);
        float E2 = fminf(d2 + 1.0f, d1 + cc2);
        float E3 = fminf(d3 + 1.0f, d2 + cc3);

        // F[j] = E[j] - j ; local inclusive prefix-min over the 4 columns
        float p0 = E0 - j0;
        float p1 = fminf(p0, E1 - (j0 + 1.0f));
        float p2 = fminf(p1, E2 - (j0 + 2.0f));
        float p3 = fminf(p2, E3 - (j0 + 3.0f));

        // Wave-wide inclusive prefix-min of per-lane totals
        float t = p3;
        #pragma unroll
        for (int dlt = 1; dlt < 64; dlt <<= 1) {
            float v = __shfl_up(t, dlt);
            if (lane >= dlt) t = fminf(t, v);
        }
        float carry = __shfl_up(t, 1);     // exclusive carry from lanes < l
        if (lane == 0) carry = 1e30f;
        carry = fminf(carry, im1 + 1.0f);  // F_full[0] = E_full[0] - 0 = i

        // D[j] = min(carry, local_prefix) + j
        d0 = fminf(carry, p0) + j0;
        d1 = fminf(carry, p1) + (j0 + 1.0f);
        d2 = fminf(carry, p2) + (j0 + 2.0f);
        d3 = fminf(carry, p3) + (j0 + 3.0f);
    }

    // Extract D[xl][yl].  (If xl==0 the loop didn't run and d* hold D0 = j.)
    if (yl == 0) {
        if (lane == 0) out[b] = (float)xl;
    } else {
        int jl = yl - 1;                   // 0..LY-2 ; owner lane jl>>2, slot jl&3
        if (lane == (jl >> 2)) {
            float r;
            switch (jl & 3) {
                case 0: r = d0; break;
                case 1: r = d1; break;
                case 2: r = d2; break;
                default: r = d3; break;
            }
            out[b] = r;
        }
    }
}

extern "C" void kernel_launch(void* const* d_in, const int* in_sizes, int n_in,
                              void* d_out, int out_size, void* d_ws, size_t ws_size,
                              hipStream_t stream) {
    const float* P  = (const float*)d_in[0];
    const int* xs   = (const int*)d_in[1];
    const int* ys   = (const int*)d_in[2];
    const int* xlen = (const int*)d_in[3];
    const int* ylen = (const int*)d_in[4];
    float* out = (float*)d_out;
    float* C = (float*)d_ws;   // S_DIM * A_DIM floats = 48 KiB

    softmax_kernel<<<S_DIM, 64, 0, stream>>>(P, C);
    dp_kernel<<<B_DIM, 64, 0, stream>>>(C, xs, ys, xlen, ylen, out);
}

// Round 2
// 153.112 us; speedup vs baseline: 1.6980x; 1.6980x over previous
//
#include <hip/hip_runtime.h>

#define S_DIM 128
#define A_DIM 96
#define B_DIM 256
#define LX 512
#define LY 256

#define FINF __builtin_inff()

// DPP helper: old kept where source invalid / row masked out.
template <int CTRL, int ROWMASK = 0xF>
__device__ __forceinline__ float upd_dpp(float oldv, float src) {
    return __int_as_float(__builtin_amdgcn_update_dpp(
        __float_as_int(oldv), __float_as_int(src), CTRL, ROWMASK, 0xF, false));
}
// DPP ctrl codes (gfx9/CDNA): row_shr:N = 0x110+N, wave_shr:1 = 0x138,
// row_bcast:15 = 0x142, row_bcast:31 = 0x143.

// Kernel A: C[x][y] = 1 - softmax(P, axis=1)[x][y].  One wave per row of P.
__global__ __launch_bounds__(64) void softmax_kernel(const float* __restrict__ P,
                                                     float* __restrict__ C) {
    int row = blockIdx.x;
    int lane = threadIdx.x;
    const float* p = P + row * A_DIM;
    float v0 = p[lane];
    float v1 = (lane < A_DIM - 64) ? p[64 + lane] : -1e30f;
    float m = fmaxf(v0, v1);
    #pragma unroll
    for (int d = 32; d > 0; d >>= 1) m = fmaxf(m, __shfl_xor(m, d));
    float e0 = expf(v0 - m);
    float e1 = (lane < A_DIM - 64) ? expf(v1 - m) : 0.0f;
    float s = e0 + e1;
    #pragma unroll
    for (int d = 32; d > 0; d >>= 1) s += __shfl_xor(s, d);
    float inv = 1.0f / s;
    C[row * A_DIM + lane] = 1.0f - e0 * inv;
    if (lane < A_DIM - 64) C[row * A_DIM + 64 + lane] = 1.0f - e1 * inv;
}

// One DP row update. Uses/updates d0..d3, reads costs C0..C3 for this row.
#define ROW_STEP(C0, C1, C2, C3, ivar)                                    \
    {                                                                     \
        float im1 = (float)((ivar) - 1);                                  \
        float left = upd_dpp<0x138>(im1, d3); /* wave_shr:1, lane0=i-1 */ \
        float E0 = fminf(d0 + 1.0f, left + (C0));                         \
        float E1 = fminf(d1 + 1.0f, d0 + (C1));                           \
        float E2 = fminf(d2 + 1.0f, d1 + (C2));                           \
        float E3 = fminf(d3 + 1.0f, d2 + (C3));                           \
        float p0 = E0 - j0;                                               \
        float p1 = fminf(p0, E1 - (j0 + 1.0f));                           \
        float p2 = fminf(p1, E2 - (j0 + 2.0f));                           \
        float p3 = fminf(p2, E3 - (j0 + 3.0f));                           \
        float t = p3;                                                     \
        t = fminf(t, upd_dpp<0x111>(FINF, t)); /* row_shr:1 */            \
        t = fminf(t, upd_dpp<0x112>(FINF, t)); /* row_shr:2 */            \
        t = fminf(t, upd_dpp<0x114>(FINF, t)); /* row_shr:4 */            \
        t = fminf(t, upd_dpp<0x118>(FINF, t)); /* row_shr:8 */            \
        t = fminf(t, upd_dpp<0x142, 0xA>(FINF, t)); /* bcast15 -> rows 1,3 */ \
        t = fminf(t, upd_dpp<0x143, 0xC>(FINF, t)); /* bcast31 -> rows 2,3 */ \
        float carry = upd_dpp<0x138>(FINF, t); /* exclusive: wave_shr:1 */ \
        carry = fminf(carry, im1 + 1.0f);      /* F_full[0] = i */        \
        d0 = fminf(carry, p0) + j0;                                       \
        d1 = fminf(carry, p1) + (j0 + 1.0f);                              \
        d2 = fminf(carry, p2) + (j0 + 2.0f);                              \
        d3 = fminf(carry, p3) + (j0 + 3.0f);                              \
    }

// Kernel B: one wave per batch element. Lane l owns columns 4l+1..4l+4.
__global__ __launch_bounds__(64) void dp_kernel(const float* __restrict__ C,
                                                const int* __restrict__ xs,
                                                const int* __restrict__ ys,
                                                const int* __restrict__ xlen,
                                                const int* __restrict__ ylen,
                                                float* __restrict__ out) {
    __shared__ float sC[S_DIM * A_DIM];  // 48 KiB cost table
    __shared__ int sX[LX + 8];           // xs for this batch (+pad)

    int b = blockIdx.x;
    int lane = threadIdx.x;

    // --- stage cost table + xs into LDS ---
    {
        const float4* Cg4 = reinterpret_cast<const float4*>(C);
        float4* sC4 = reinterpret_cast<float4*>(sC);
        #pragma unroll
        for (int k = 0; k < (S_DIM * A_DIM) / (4 * 64); ++k)
            sC4[lane + 64 * k] = Cg4[lane + 64 * k];
        const int* xsb = xs + b * LX;
        #pragma unroll
        for (int k = 0; k < LX / 64; ++k)
            sX[lane + 64 * k] = xsb[lane + 64 * k];
        if (lane < 8) sX[LX + lane] = 0;
    }
    __syncthreads();

    int xl = xlen[b] - 1;  // rows 1..xl
    int yl = ylen[b] - 1;  // output column

    int4 yv = *reinterpret_cast<const int4*>(ys + b * LY + lane * 4);
    int y0 = yv.x, y1 = yv.y, y2 = yv.z, y3 = yv.w;

    float j0 = (float)(4 * lane + 1);
    float d0 = j0, d1 = j0 + 1.0f, d2 = j0 + 2.0f, d3 = j0 + 3.0f;

    // --- pipeline prologue: costs for rows 1,2; x for rows 3,4 ---
    int xA = sX[0];
    int xB = sX[1];
    int xA2 = sX[2];
    int xB2 = sX[3];
    float A0 = sC[xA * A_DIM + y0], A1 = sC[xA * A_DIM + y1];
    float A2 = sC[xA * A_DIM + y2], A3 = sC[xA * A_DIM + y3];
    float B0 = sC[xB * A_DIM + y0], B1 = sC[xB * A_DIM + y1];
    float B2 = sC[xB * A_DIM + y2], B3 = sC[xB * A_DIM + y3];

    int i = 1;
    for (; i + 1 <= xl; i += 2) {
        // prefetch costs for rows i+2, i+3 (consumed next iteration)
        int baseA = xA2 * A_DIM, baseB = xB2 * A_DIM;
        float nA0 = sC[baseA + y0], nA1 = sC[baseA + y1];
        float nA2 = sC[baseA + y2], nA3 = sC[baseA + y3];
        float nB0 = sC[baseB + y0], nB1 = sC[baseB + y1];
        float nB2 = sC[baseB + y2], nB3 = sC[baseB + y3];
        // prefetch x for rows i+4, i+5 (consumed next iteration's prefetch)
        int nxA = sX[i + 3];
        int nxB = sX[i + 4];

        ROW_STEP(A0, A1, A2, A3, i);
        ROW_STEP(B0, B1, B2, B3, i + 1);

        A0 = nA0; A1 = nA1; A2 = nA2; A3 = nA3;
        B0 = nB0; B1 = nB1; B2 = nB2; B3 = nB3;
        xA2 = nxA; xB2 = nxB;
    }
    if (i <= xl) {  // odd tail
        ROW_STEP(A0, A1, A2, A3, i);
    }

    // --- extract D[xl][yl] ---
    if (yl == 0) {
        if (lane == 0) out[b] = (float)xl;
    } else {
        int jl = yl - 1;  // owner lane jl>>2, slot jl&3
        if (lane == (jl >> 2)) {
            float r;
            switch (jl & 3) {
                case 0: r = d0; break;
                case 1: r = d1; break;
                case 2: r = d2; break;
                default: r = d3; break;
            }
            out[b] = r;
        }
    }
}

extern "C" void kernel_launch(void* const* d_in, const int* in_sizes, int n_in,
                              void* d_out, int out_size, void* d_ws, size_t ws_size,
                              hipStream_t stream) {
    const float* P  = (const float*)d_in[0];
    const int* xs   = (const int*)d_in[1];
    const int* ys   = (const int*)d_in[2];
    const int* xlen = (const int*)d_in[3];
    const int* ylen = (const int*)d_in[4];
    float* out = (float*)d_out;
    float* C = (float*)d_ws;  // S_DIM * A_DIM floats

    softmax_kernel<<<S_DIM, 64, 0, stream>>>(P, C);
    dp_kernel<<<B_DIM, 64, 0, stream>>>(C, xs, ys, xlen, ylen, out);
}

// Round 3
// 110.877 us; speedup vs baseline: 2.3448x; 1.3809x over previous
//
#include <hip/hip_runtime.h>

#define S_DIM 128
#define A_DIM 96
#define B_DIM 256
#define LX 512
#define LY 256

// DPP helper: old kept where source invalid.
template <int CTRL, int ROWMASK = 0xF>
__device__ __forceinline__ float upd_dpp(float oldv, float src) {
    return __int_as_float(__builtin_amdgcn_update_dpp(
        __float_as_int(oldv), __float_as_int(src), CTRL, ROWMASK, 0xF, false));
}
// 0x138 = wave_shr:1

// Cm1[x][y] = -softmax(P, axis=1)[x][y]   ( = cost - 1 )
__global__ __launch_bounds__(64) void softmax_kernel(const float* __restrict__ P,
                                                     float* __restrict__ C) {
    int row = blockIdx.x, lane = threadIdx.x;
    const float* p = P + row * A_DIM;
    float v0 = p[lane];
    float v1 = (lane < A_DIM - 64) ? p[64 + lane] : -1e30f;
    float m = fmaxf(v0, v1);
    #pragma unroll
    for (int d = 32; d > 0; d >>= 1) m = fmaxf(m, __shfl_xor(m, d));
    float e0 = expf(v0 - m);
    float e1 = (lane < A_DIM - 64) ? expf(v1 - m) : 0.0f;
    float s = e0 + e1;
    #pragma unroll
    for (int d = 32; d > 0; d >>= 1) s += __shfl_xor(s, d);
    float inv = 1.0f / s;
    C[row * A_DIM + lane] = -(e0 * inv);
    if (lane < A_DIM - 64) C[row * A_DIM + 64 + lane] = -(e1 * inv);
}

__device__ __forceinline__ int clampi(int v, int hi) {
    return v < 0 ? 0 : (v > hi ? hi : v);
}

// Wavefront DP: lane l owns columns 4l+1..4l+4; at step t it processes row
// i = t - lane. State kept in f-domain: f = D - j (row 0 => f = 0).
__global__ __launch_bounds__(64) void dp_kernel(const float* __restrict__ C,
                                                const int* __restrict__ xs,
                                                const int* __restrict__ ys,
                                                const int* __restrict__ xlen,
                                                const int* __restrict__ ylen,
                                                float* __restrict__ out) {
    __shared__ float sC[S_DIM * A_DIM];   // holds (c - 1) = -p
    __shared__ int sX[LX];                // xs * A_DIM (pre-scaled)

    int b = blockIdx.x, lane = threadIdx.x;
    {
        const float4* Cg4 = (const float4*)C;
        float4* sC4 = (float4*)sC;
        #pragma unroll
        for (int k = 0; k < (S_DIM * A_DIM) / (4 * 64); ++k)
            sC4[lane + 64 * k] = Cg4[lane + 64 * k];
        const int* xsb = xs + b * LX;
        #pragma unroll
        for (int k = 0; k < LX / 64; ++k)
            sX[lane + 64 * k] = xsb[lane + 64 * k] * A_DIM;
    }
    __syncthreads();

    int xl = xlen[b] - 1;   // rows 1..xl       (>=1 per setup)
    int yl = ylen[b] - 1;   // answer column    (>=1 per setup)
    int4 yv = *(const int4*)(ys + b * LY + lane * 4);
    int y0 = yv.x, y1 = yv.y, y2 = yv.z, y3 = yv.w;

    int lane_ans = (yl - 1) >> 2;
    int t_end = xl + lane_ans;

    float f0 = 0.f, f1 = 0.f, f2 = 0.f, f3 = 0.f;
    int iu = -lane;   // iu = i - 1 where i = row this lane processes at step t=1

    // ---- prologue pipeline fill (clamped indices are garbage-safe: gated) ----
    int xm = sX[clampi(iu, LX - 1)];       // costs for M(row i) consumed in step 1
    float m0 = sC[xm + y0], m1 = sC[xm + y1], m2 = sC[xm + y2], m3 = sC[xm + y3];
    int x1 = sX[clampi(iu + 1, LX - 1)];   // consumed end of step 1
    float ccA0 = sC[x1 + y0], ccA1 = sC[x1 + y1], ccA2 = sC[x1 + y2], ccA3 = sC[x1 + y3];
    int x2 = sX[clampi(iu + 2, LX - 1)];   // consumed end of step 2
    float ccB0 = sC[x2 + y0], ccB1 = sC[x2 + y1], ccB2 = sC[x2 + y2], ccB3 = sC[x2 + y3];
    int xA = sX[clampi(iu + 3, LX - 1)];   // gathers issued at t=1
    int xB = sX[clampi(iu + 4, LX - 1)];   // gathers issued at t=2

    // M terms for step 1: fp = 0, prev diag = 0
    float pA0 = 1.f, pA1 = 1.f, pA2 = 1.f, pA3 = 1.f;
    float pB0 = m0, pB1 = m1, pB2 = m2, pB3 = m3;

    float tf = 1.0f;          // (float)t
    bool l0 = (lane == 0);

    int t = 1;
    for (; t + 1 <= t_end; t += 2) {
        // ---------- phase A: step t ----------
        int xnA = sX[clampi(iu + 5, LX - 1)];
        float g0 = sC[xA + y0], g1 = sC[xA + y1], g2 = sC[xA + y2], g3 = sC[xA + y3];
        float Lf = upd_dpp<0x138>(0.f, f3);
        Lf = l0 ? tf : Lf;                       // f[i][0] = i for lane 0
        float v0 = fminf(fminf(Lf, pA0), pB0);
        float v1 = fminf(fminf(v0, pA1), pB1);
        float v2 = fminf(fminf(v1, pA2), pB2);
        float v3 = fminf(fminf(v2, pA3), pB3);
        bool act = (unsigned)iu < (unsigned)xl;  // 1 <= i <= xl
        f0 = act ? v0 : f0;
        f1 = act ? v1 : f1;
        f2 = act ? v2 : f2;
        f3 = act ? v3 : f3;
        pA0 = f0 + 1.f; pB0 = Lf + ccA0;
        pA1 = f1 + 1.f; pB1 = f0 + ccA1;
        pA2 = f2 + 1.f; pB2 = f1 + ccA2;
        pA3 = f3 + 1.f; pB3 = f2 + ccA3;
        ccA0 = g0; ccA1 = g1; ccA2 = g2; ccA3 = g3;
        xA = xnA;
        iu += 1; tf += 1.f;
        // ---------- phase B: step t+1 ----------
        int xnB = sX[clampi(iu + 5, LX - 1)];
        float h0 = sC[xB + y0], h1 = sC[xB + y1], h2 = sC[xB + y2], h3 = sC[xB + y3];
        Lf = upd_dpp<0x138>(0.f, f3);
        Lf = l0 ? tf : Lf;
        v0 = fminf(fminf(Lf, pA0), pB0);
        v1 = fminf(fminf(v0, pA1), pB1);
        v2 = fminf(fminf(v1, pA2), pB2);
        v3 = fminf(fminf(v2, pA3), pB3);
        act = (unsigned)iu < (unsigned)xl;
        f0 = act ? v0 : f0;
        f1 = act ? v1 : f1;
        f2 = act ? v2 : f2;
        f3 = act ? v3 : f3;
        pA0 = f0 + 1.f; pB0 = Lf + ccB0;
        pA1 = f1 + 1.f; pB1 = f0 + ccB1;
        pA2 = f2 + 1.f; pB2 = f1 + ccB2;
        pA3 = f3 + 1.f; pB3 = f2 + ccB3;
        ccB0 = h0; ccB1 = h1; ccB2 = h2; ccB3 = h3;
        xB = xnB;
        iu += 1; tf += 1.f;
    }
    if (t <= t_end) {   // tail single step (odd t; consumes phase-B-produced pA/pB)
        float Lf = upd_dpp<0x138>(0.f, f3);
        Lf = l0 ? tf : Lf;
        float v0 = fminf(fminf(Lf, pA0), pB0);
        float v1 = fminf(fminf(v0, pA1), pB1);
        float v2 = fminf(fminf(v1, pA2), pB2);
        float v3 = fminf(fminf(v2, pA3), pB3);
        bool act = (unsigned)iu < (unsigned)xl;
        f0 = act ? v0 : f0;
        f1 = act ? v1 : f1;
        f2 = act ? v2 : f2;
        f3 = act ? v3 : f3;
    }

    if (lane == lane_ans) {
        int slot = (yl - 1) & 3;
        float r = (slot == 0) ? f0 : (slot == 1) ? f1 : (slot == 2) ? f2 : f3;
        out[b] = r + (float)yl;   // back to D-domain: D = f + j
    }
}

extern "C" void kernel_launch(void* const* d_in, const int* in_sizes, int n_in,
                              void* d_out, int out_size, void* d_ws, size_t ws_size,
                              hipStream_t stream) {
    const float* P  = (const float*)d_in[0];
    const int* xs   = (const int*)d_in[1];
    const int* ys   = (const int*)d_in[2];
    const int* xlen = (const int*)d_in[3];
    const int* ylen = (const int*)d_in[4];
    float* out = (float*)d_out;
    float* C = (float*)d_ws;  // S_DIM * A_DIM floats, holds -softmax(P)

    softmax_kernel<<<S_DIM, 64, 0, stream>>>(P, C);
    dp_kernel<<<B_DIM, 64, 0, stream>>>(C, xs, ys, xlen, ylen, out);
}

// Round 5
// 94.155 us; speedup vs baseline: 2.7612x; 1.1776x over previous
//
#include <hip/hip_runtime.h>

#define S_DIM 128
#define A_DIM 96
#define B_DIM 256
#define LX 512
#define LY 256
#define PADL 64
#define PADR 96

// DPP move: lanes with invalid source keep `oldv`. 0x138 = wave_shr:1.
template <int CTRL>
__device__ __forceinline__ float dpp_mov(float oldv, float src) {
    return __int_as_float(__builtin_amdgcn_update_dpp(
        __float_as_int(oldv), __float_as_int(src), CTRL, 0xF, 0xF, false));
}

// Table[x][y] = cost - 2 = -1 - softmax(P,axis=1)[x][y]  (g-domain costs)
__global__ __launch_bounds__(64) void softmax_kernel(const float* __restrict__ P,
                                                     float* __restrict__ C) {
    int row = blockIdx.x, lane = threadIdx.x;
    const float* p = P + row * A_DIM;
    float v0 = p[lane];
    float v1 = (lane < A_DIM - 64) ? p[64 + lane] : -1e30f;
    float m = fmaxf(v0, v1);
    #pragma unroll
    for (int d = 32; d > 0; d >>= 1) m = fmaxf(m, __shfl_xor(m, d));
    float e0 = expf(v0 - m);
    float e1 = (lane < A_DIM - 64) ? expf(v1 - m) : 0.0f;
    float s = e0 + e1;
    #pragma unroll
    for (int d = 32; d > 0; d >>= 1) s += __shfl_xor(s, d);
    float inv = 1.0f / s;
    C[row * A_DIM + lane] = -1.0f - e0 * inv;
    if (lane < A_DIM - 64) C[row * A_DIM + 64 + lane] = -1.0f - e1 * inv;
}

// One wavefront phase in g-domain (g = D - i - j):
//   g[i][j] = min(g[i][j-1], g[i-1][j], g[i-1][j-1] + (c-2))
// Lane l owns cols 4l+1..4l+4; at phase tau it processes row i = tau - l.
// pB holds the diag terms prepared at the end of the previous phase.
#define PHASE(Q0, Q1, Q2, Q3)                            \
    {                                                    \
        float Lf = dpp_mov<0x138>(0.0f, g3);             \
        float v0 = fminf(fminf(Lf, g0), pB0);            \
        float v1 = fminf(fminf(v0, g1), pB1);            \
        float v2 = fminf(fminf(v1, g2), pB2);            \
        float v3 = fminf(fminf(v2, g3), pB3);            \
        bool act = (unsigned)iu < xl_u;                  \
        g0 = act ? v0 : g0;                              \
        g1 = act ? v1 : g1;                              \
        g2 = act ? v2 : g2;                              \
        g3 = act ? v3 : g3;                              \
        iu += 1;                                         \
        pB0 = Lf + (Q0);                                 \
        pB1 = g0 + (Q1);                                 \
        pB2 = g1 + (Q2);                                 \
        pB3 = g2 + (Q3);                                 \
    }

#define SB() __builtin_amdgcn_sched_barrier(0x7)  // pin DS order; ALU may cross

__global__ __launch_bounds__(64) void dp_kernel(const float* __restrict__ C,
                                                const int* __restrict__ xs,
                                                const int* __restrict__ ys,
                                                const int* __restrict__ xlen,
                                                const int* __restrict__ ylen,
                                                float* __restrict__ out) {
    __shared__ float sC[S_DIM * A_DIM];        // (c-2) table, byte-addressed
    __shared__ int sXbuf[PADL + LX + PADR];    // xs pre-scaled to byte offsets

    int b = blockIdx.x, lane = threadIdx.x;
    {
        const float4* Cg4 = (const float4*)C;
        float4* sC4 = (float4*)sC;
        #pragma unroll
        for (int k = 0; k < (S_DIM * A_DIM) / (4 * 64); ++k)
            sC4[lane + 64 * k] = Cg4[lane + 64 * k];
        const int* xsb = xs + b * LX;
        int* sXw = sXbuf + PADL;
        #pragma unroll
        for (int k = 0; k < LX / 64; ++k)
            sXw[lane + 64 * k] = xsb[lane + 64 * k] * (A_DIM * 4);
        sXbuf[lane] = 0;                               // left pad
        sXbuf[PADL + LX + lane] = 0;                   // right pad 0..63
        if (lane < PADR - 64) sXbuf[PADL + LX + 64 + lane] = 0;  // 64..95
    }
    __syncthreads();

    int xl = xlen[b] - 1;          // rows 1..xl (>=1)
    int yl = ylen[b] - 1;          // answer column (>=1)
    unsigned xl_u = (unsigned)xl;
    int4 yv = *(const int4*)(ys + b * LY + lane * 4);
    int yb0 = yv.x * 4, yb1 = yv.y * 4, yb2 = yv.z * 4, yb3 = yv.w * 4;
    int lane_ans = (yl - 1) >> 2;
    int t_end = xl + lane_ans;
    int iu = -lane;                // iu = (phase-1) - lane = row-1
    const int* sXp = sXbuf + PADL;
    const char* sCB = (const char*)sC;

#define LDC(XB, YB) (*(const float*)(sCB + (unsigned)((XB) + (YB))))

    // ---- prologue: fill stages S0..S2 (phases 1..3), xv0..2 (phases 4..6) ----
    int xm  = sXp[iu];
    int xa0 = sXp[iu + 1], xa1 = sXp[iu + 2], xa2 = sXp[iu + 3];
    int xv0 = sXp[iu + 4], xv1 = sXp[iu + 5], xv2 = sXp[iu + 6];
    float pB0 = LDC(xm, yb0), pB1 = LDC(xm, yb1), pB2 = LDC(xm, yb2), pB3 = LDC(xm, yb3);
    float s00 = LDC(xa0, yb0), s01 = LDC(xa0, yb1), s02 = LDC(xa0, yb2), s03 = LDC(xa0, yb3);
    float s10 = LDC(xa1, yb0), s11 = LDC(xa1, yb1), s12 = LDC(xa1, yb2), s13 = LDC(xa1, yb3);
    float s20 = LDC(xa2, yb0), s21 = LDC(xa2, yb1), s22 = LDC(xa2, yb2), s23 = LDC(xa2, yb3);
    float s30, s31, s32, s33;
    int xv3;
    float g0 = 0.f, g1 = 0.f, g2 = 0.f, g3 = 0.f;

    // ---- main loop: 4 phases/iter; stage issued 3 phases before consumption;
    //      every lgkmcnt wait has <=14 younger DS ops (exactly expressible) ----
    int T = 1;
    for (; T + 3 <= t_end; T += 4) {
        PHASE(s00, s01, s02, s03);                 // phase T
        SB();
        s30 = LDC(xv0, yb0); s31 = LDC(xv0, yb1);  // stage for phase T+3
        s32 = LDC(xv0, yb2); s33 = LDC(xv0, yb3);
        xv3 = sXp[iu + 6];                         // x for phase T+6
        SB();
        PHASE(s10, s11, s12, s13);                 // phase T+1
        SB();
        s00 = LDC(xv1, yb0); s01 = LDC(xv1, yb1);  // stage for phase T+4
        s02 = LDC(xv1, yb2); s03 = LDC(xv1, yb3);
        xv0 = sXp[iu + 6];                         // x for phase T+7
        SB();
        PHASE(s20, s21, s22, s23);                 // phase T+2
        SB();
        s10 = LDC(xv2, yb0); s11 = LDC(xv2, yb1);  // stage for phase T+5
        s12 = LDC(xv2, yb2); s13 = LDC(xv2, yb3);
        xv1 = sXp[iu + 6];                         // x for phase T+8
        SB();
        PHASE(s30, s31, s32, s33);                 // phase T+3
        SB();
        s20 = LDC(xv3, yb0); s21 = LDC(xv3, yb1);  // stage for phase T+6
        s22 = LDC(xv3, yb2); s23 = LDC(xv3, yb3);
        xv2 = sXp[iu + 6];                         // x for phase T+9
        SB();
    }
    // ---- tail: at most 3 phases, stages S0..S2 are valid for T..T+2 ----
    if (T <= t_end) { PHASE(s00, s01, s02, s03); ++T; }
    if (T <= t_end) { PHASE(s10, s11, s12, s13); ++T; }
    if (T <= t_end) { PHASE(s20, s21, s22, s23); }

    // ---- answer: D[xl][yl] = g + xl + yl ----
    if (lane == lane_ans) {
        int slot = (yl - 1) & 3;
        float r = (slot == 0) ? g0 : (slot == 1) ? g1 : (slot == 2) ? g2 : g3;
        out[b] = r + (float)(xl + yl);
    }
}

extern "C" void kernel_launch(void* const* d_in, const int* in_sizes, int n_in,
                              void* d_out, int out_size, void* d_ws, size_t ws_size,
                              hipStream_t stream) {
    const float* P  = (const float*)d_in[0];
    const int* xs   = (const int*)d_in[1];
    const int* ys   = (const int*)d_in[2];
    const int* xlen = (const int*)d_in[3];
    const int* ylen = (const int*)d_in[4];
    float* out = (float*)d_out;
    float* C = (float*)d_ws;  // S_DIM*A_DIM floats, holds -1 - softmax(P)

    softmax_kernel<<<S_DIM, 64, 0, stream>>>(P, C);
    dp_kernel<<<B_DIM, 64, 0, stream>>>(C, xs, ys, xlen, ylen, out);
}

// Round 7
// 91.840 us; speedup vs baseline: 2.8308x; 1.0252x over previous
//
#include <hip/hip_runtime.h>

#define S_DIM 128
#define A_DIM 96
#define B_DIM 256
#define LX 512
#define LY 256
#define PADL 64
#define PADR 96

// DPP move: lanes with invalid source keep `oldv`. 0x138 = wave_shr:1.
template <int CTRL>
__device__ __forceinline__ float dpp_mov(float oldv, float src) {
    return __int_as_float(__builtin_amdgcn_update_dpp(
        __float_as_int(oldv), __float_as_int(src), CTRL, 0xF, 0xF, false));
}

// Table[x][y] = cost - 2 = -1 - softmax(P,axis=1)[x][y]  (g-domain costs)
__global__ __launch_bounds__(64) void softmax_kernel(const float* __restrict__ P,
                                                     float* __restrict__ C) {
    int row = blockIdx.x, lane = threadIdx.x;
    const float* p = P + row * A_DIM;
    float v0 = p[lane];
    float v1 = (lane < A_DIM - 64) ? p[64 + lane] : -1e30f;
    float m = fmaxf(v0, v1);
    #pragma unroll
    for (int d = 32; d > 0; d >>= 1) m = fmaxf(m, __shfl_xor(m, d));
    float e0 = expf(v0 - m);
    float e1 = (lane < A_DIM - 64) ? expf(v1 - m) : 0.0f;
    float s = e0 + e1;
    #pragma unroll
    for (int d = 32; d > 0; d >>= 1) s += __shfl_xor(s, d);
    float inv = 1.0f / s;
    C[row * A_DIM + lane] = -1.0f - e0 * inv;
    if (lane < A_DIM - 64) C[row * A_DIM + 64 + lane] = -1.0f - e1 * inv;
}

// g-domain wavefront phase (g = D - i - j), no activity gating:
//   g[i][j] = min(g[i][j-1], g[i-1][j], g[i-1][j-1] + (c-2))
// Pre-start rows are protected by the +inf cost row; post-xl rows produce
// garbage that provably never flows back into rows <= xl.
// Reassociated min tree: cross-phase chain is DPP -> v1 -> v3 only.
#define PHASE(Q0, Q1, Q2, Q3)                               \
    {                                                       \
        float m1  = fminf(g1, pB1);                         \
        float m2  = fminf(g2, pB2);                         \
        float m3  = fminf(g3, pB3);                         \
        float t01 = fminf(fminf(g0, pB0), m1);              \
        float t23 = fminf(m2, m3);                          \
        float Lf  = dpp_mov<0x138>(0.0f, g3);               \
        float v0  = fminf(fminf(Lf, g0), pB0);              \
        float v1  = fminf(Lf, t01);                         \
        float v2  = fminf(v1, m2);                          \
        float v3  = fminf(v1, t23);                         \
        g0 = v0; g1 = v1; g2 = v2; g3 = v3;                 \
        pB0 = Lf + (Q0);                                    \
        pB1 = v0 + (Q1);                                    \
        pB2 = v1 + (Q2);                                    \
        pB3 = v2 + (Q3);                                    \
    }

#define SB() __builtin_amdgcn_sched_barrier(0x7)  // pin DS/VMEM order; ALU may cross

__global__ __launch_bounds__(64) void dp_kernel(const float* __restrict__ C,
                                                const int* __restrict__ xs,
                                                const int* __restrict__ ys,
                                                const int* __restrict__ xlen,
                                                const int* __restrict__ ylen,
                                                float* __restrict__ out) {
    __shared__ float sC[(S_DIM + 1) * A_DIM];   // (c-2) table + one +inf row
    __shared__ int sXbuf[PADL + LX + PADR];     // xs pre-scaled to byte offsets

    int b = blockIdx.x, lane = threadIdx.x;
    {
        const float4* Cg4 = (const float4*)C;
        float4* sC4 = (float4*)sC;
        #pragma unroll
        for (int k = 0; k < (S_DIM * A_DIM) / (4 * 64); ++k)
            sC4[lane + 64 * k] = Cg4[lane + 64 * k];
        // +inf row (row index S_DIM): guards pre-start phases
        float INF = __builtin_inff();
        sC[S_DIM * A_DIM + lane] = INF;
        if (lane < A_DIM - 64) sC[S_DIM * A_DIM + 64 + lane] = INF;
        const int* xsb = xs + b * LX;
        int* sXw = sXbuf + PADL;
        #pragma unroll
        for (int k = 0; k < LX / 64; ++k)
            sXw[lane + 64 * k] = xsb[lane + 64 * k] * (A_DIM * 4);
        sXbuf[lane] = S_DIM * A_DIM * 4;               // left pad -> +inf row
        sXbuf[PADL + LX + lane] = 0;                   // right pad -> row 0 (finite)
        if (lane < PADR - 64) sXbuf[PADL + LX + 64 + lane] = 0;
    }
    __syncthreads();

    int xl = xlen[b] - 1;          // rows 1..xl (>=1)
    int yl = ylen[b] - 1;          // answer column (>=1)
    int4 yv = *(const int4*)(ys + b * LY + lane * 4);
    int yb0 = yv.x * 4, yb1 = yv.y * 4, yb2 = yv.z * 4, yb3 = yv.w * 4;
    int lane_ans = (yl - 1) >> 2;
    int t_end = xl + lane_ans;
    const int* sXp0 = sXbuf + PADL - lane;   // index p -> x for row p (iu = p-1... row p uses xs[p-1])
    const char* sCB = (const char*)sC;

#define LDC(XB, YB) (*(const float*)(sCB + (unsigned)((XB) + (YB))))

    // ---- prologue: pB for phase 1; stages S0..S2 (phases 1..3); xv0..3 (phases 4..7) ----
    int xm  = sXp0[0];
    int xa0 = sXp0[1], xa1 = sXp0[2], xa2 = sXp0[3];
    int xv0 = sXp0[4], xv1 = sXp0[5], xv2 = sXp0[6], xv3 = sXp0[7];
    const int* sxp8 = sXp0 + 8;
    float pB0 = LDC(xm, yb0), pB1 = LDC(xm, yb1), pB2 = LDC(xm, yb2), pB3 = LDC(xm, yb3);
    float s00 = LDC(xa0, yb0), s01 = LDC(xa0, yb1), s02 = LDC(xa0, yb2), s03 = LDC(xa0, yb3);
    float s10 = LDC(xa1, yb0), s11 = LDC(xa1, yb1), s12 = LDC(xa1, yb2), s13 = LDC(xa1, yb3);
    float s20 = LDC(xa2, yb0), s21 = LDC(xa2, yb1), s22 = LDC(xa2, yb2), s23 = LDC(xa2, yb3);
    float s30, s31, s32, s33;
    float g0 = 0.f, g1 = 0.f, g2 = 0.f, g3 = 0.f;

    // ---- main loop: 4 phases/iter; every stage has a uniform 3-phase lead;
    //      every lgkm consumption point has exactly <=15 younger DS ops ----
    int T = 1;
    for (; T + 3 <= t_end; T += 4) {
        s30 = LDC(xv0, yb0); s31 = LDC(xv0, yb1);  // stage for phase T+3
        s32 = LDC(xv0, yb2); s33 = LDC(xv0, yb3);
        xv0 = sxp8[0];                             // x for phase T+7's stage
        SB();
        PHASE(s00, s01, s02, s03);                 // phase T
        SB();
        s00 = LDC(xv1, yb0); s01 = LDC(xv1, yb1);  // stage for phase T+4
        s02 = LDC(xv1, yb2); s03 = LDC(xv1, yb3);
        xv1 = sxp8[1];                             // x for phase T+8
        SB();
        PHASE(s10, s11, s12, s13);                 // phase T+1
        SB();
        s10 = LDC(xv2, yb0); s11 = LDC(xv2, yb1);  // stage for phase T+5
        s12 = LDC(xv2, yb2); s13 = LDC(xv2, yb3);
        xv2 = sxp8[2];                             // x for phase T+9
        SB();
        PHASE(s20, s21, s22, s23);                 // phase T+2
        SB();
        s20 = LDC(xv3, yb0); s21 = LDC(xv3, yb1);  // stage for phase T+6
        s22 = LDC(xv3, yb2); s23 = LDC(xv3, yb3);
        xv3 = sxp8[3];                             // x for phase T+10
        SB();
        PHASE(s30, s31, s32, s33);                 // phase T+3
        SB();
        sxp8 += 4;
    }
    // ---- tail: at most 3 phases; S0..S2 hold phases T..T+2 ----
    if (T <= t_end) { PHASE(s00, s01, s02, s03); ++T; }
    if (T <= t_end) { PHASE(s10, s11, s12, s13); ++T; }
    if (T <= t_end) { PHASE(s20, s21, s22, s23); }

    // ---- answer: D[xl][yl] = g + xl + yl ----
    if (lane == lane_ans) {
        int slot = (yl - 1) & 3;
        float r = (slot == 0) ? g0 : (slot == 1) ? g1 : (slot == 2) ? g2 : g3;
        out[b] = r + (float)(xl + yl);
    }
}

extern "C" void kernel_launch(void* const* d_in, const int* in_sizes, int n_in,
                              void* d_out, int out_size, void* d_ws, size_t ws_size,
                              hipStream_t stream) {
    const float* P  = (const float*)d_in[0];
    const int* xs   = (const int*)d_in[1];
    const int* ys   = (const int*)d_in[2];
    const int* xlen = (const int*)d_in[3];
    const int* ylen = (const int*)d_in[4];
    float* out = (float*)d_out;
    float* C = (float*)d_ws;  // S_DIM*A_DIM floats, holds -1 - softmax(P)

    softmax_kernel<<<S_DIM, 64, 0, stream>>>(P, C);
    dp_kernel<<<B_DIM, 64, 0, stream>>>(C, xs, ys, xlen, ylen, out);
}

// Round 9
// 87.863 us; speedup vs baseline: 2.9589x; 1.0453x over previous
//
#include <hip/hip_runtime.h>

#define S_DIM 128
#define A_DIM 96
#define B_DIM 256
#define LX 512
#define LY 256

// Dynamic-LDS layout (byte offsets from base):
//   [0, 132096)        packed cost quads: 129 rows x 64 lanes x 16B (row 128 = +inf)
//   [82944, 132096)    transient fp32 staging of C (48KB) during construction
//                      (overlap-safe within the single wave: DS ops execute in
//                      program order, and write of packed row x ends before the
//                      staging bytes it overlaps are ever re-read)
//   [132096, 136704)   sX: 1152 ints = packed-row byte offsets (256 left pad -> inf row,
//                      512 xs entries, right pad -> row 0)
#define PK_ROWB   1024u
#define INF_ROW   128
#define STG_OFF   82944u
#define SX_OFF    132096u
#define LDS_BYTES 136704

typedef float f32x4 __attribute__((ext_vector_type(4)));
typedef int   i32x4 __attribute__((ext_vector_type(4)));

template <int CTRL>
__device__ __forceinline__ float dpp_mov(float oldv, float src) {
    return __int_as_float(__builtin_amdgcn_update_dpp(
        __float_as_int(oldv), __float_as_int(src), CTRL, 0xF, 0xF, false));
}
#define DPP_SHR1(o, s) dpp_mov<0x138>((o), (s))   // lane l <- lane l-1 ; lane0 <- o

__device__ __forceinline__ f32x4 ds_load4(uint32_t addr) {
    f32x4 v;
    asm volatile("ds_read_b128 %0, %1" : "=v"(v) : "v"(addr));
    return v;
}
__device__ __forceinline__ i32x4 ds_load4i(uint32_t addr) {
    i32x4 v;
    asm volatile("ds_read_b128 %0, %1" : "=v"(v) : "v"(addr));
    return v;
}
// Counted wait (pure-DS traffic, in-order completion) + scheduling fence (rule #18).
#define WAITK(N) do { asm volatile("s_waitcnt lgkmcnt(" #N ")" ::: "memory"); \
                      __builtin_amdgcn_sched_barrier(0); } while (0)

// Table[x][y] = cost - 2 = -1 - softmax(P,axis=1)[x][y]  (g-domain costs)
__global__ __launch_bounds__(64) void softmax_kernel(const float* __restrict__ P,
                                                     float* __restrict__ C) {
    int row = blockIdx.x, lane = threadIdx.x;
    const float* p = P + row * A_DIM;
    float v0 = p[lane];
    float v1 = (lane < A_DIM - 64) ? p[64 + lane] : -1e30f;
    float m = fmaxf(v0, v1);
    #pragma unroll
    for (int d = 32; d > 0; d >>= 1) m = fmaxf(m, __shfl_xor(m, d));
    float e0 = expf(v0 - m);
    float e1 = (lane < A_DIM - 64) ? expf(v1 - m) : 0.0f;
    float s = e0 + e1;
    #pragma unroll
    for (int d = 32; d > 0; d >>= 1) s += __shfl_xor(s, d);
    float inv = 1.0f / s;
    C[row * A_DIM + lane] = -1.0f - e0 * inv;
    if (lane < A_DIM - 64) C[row * A_DIM + 64 + lane] = -1.0f - e1 * inv;
}

// One DP row in g-domain (g = D - i - j):
//   g[i][j] = min(g[i][j-1], g[i-1][j], g[i-1][j-1] + (c-2))
// SSd = left-neighbor g3 after row i-1 (diag), SSl = after row i (left).
#define ROWSTEP(SSd, SSl, Q)                              \
    {                                                     \
        float a0 = (SSd) + (Q).x;                         \
        float n0 = fminf(fminf((SSl), g0), a0);           \
        float a1 = g0 + (Q).y;                            \
        float n1 = fminf(fminf(n0, g1), a1);              \
        float a2 = g1 + (Q).z;                            \
        float n2 = fminf(fminf(n1, g2), a2);              \
        float a3 = g2 + (Q).w;                            \
        float n3 = fminf(fminf(n2, g3), a3);              \
        g0 = n0; g1 = n1; g2 = n2; g3 = n3;               \
    }

// Phase t: consume buffer P (costs rows of phase t), prefetch buffer Q (phase t+1)
// using xg##P (= x-quad of phase t+1, loaded 2 phases ago), reload xg##P with the
// x-quad of phase t+3. Exactly 5 DS ops issued; lgkmcnt(5) keeps only those 5.
#define PHASE_FULL(P, Q)                                          \
    {                                                             \
        q##Q##0 = ds_load4((uint32_t)xg##P.x + lane16b);          \
        q##Q##1 = ds_load4((uint32_t)xg##P.y + lane16b);          \
        q##Q##2 = ds_load4((uint32_t)xg##P.z + lane16b);          \
        q##Q##3 = ds_load4((uint32_t)xg##P.w + lane16b);          \
        xg##P = ds_load4i(xaddr); xaddr += 16u;                   \
        WAITK(5);                                                 \
        float ss0 = DPP_SHR1(0.f, h0);                            \
        float ss1 = DPP_SHR1(0.f, h1);                            \
        float ss2 = DPP_SHR1(0.f, h2);                            \
        float ss3 = DPP_SHR1(0.f, h3);                            \
        float ss4 = DPP_SHR1(0.f, g3);                            \
        h0 = g3;                                                  \
        ROWSTEP(ss0, ss1, q##P##0); h1 = g3;                      \
        ROWSTEP(ss1, ss2, q##P##1); h2 = g3;                      \
        ROWSTEP(ss2, ss3, q##P##2); h3 = g3;                      \
        ROWSTEP(ss3, ss4, q##P##3);                               \
    }

#define TAIL(P)                                                   \
    {                                                             \
        WAITK(0);                                                 \
        float ss0 = DPP_SHR1(0.f, h0);                            \
        float ss1 = DPP_SHR1(0.f, h1);                            \
        float ss2 = DPP_SHR1(0.f, h2);                            \
        float ss3 = DPP_SHR1(0.f, h3);                            \
        float ss4 = DPP_SHR1(0.f, g3);                            \
        ROWSTEP(ss0, ss1, q##P##0);                               \
        if (r_star > 0) { ROWSTEP(ss1, ss2, q##P##1);             \
          if (r_star > 1) { ROWSTEP(ss2, ss3, q##P##2);           \
            if (r_star > 2) { ROWSTEP(ss3, ss4, q##P##3); } } }   \
    }

__global__ __launch_bounds__(64) void dp_kernel(const float* __restrict__ C,
                                                const int* __restrict__ xs,
                                                const int* __restrict__ ys,
                                                const int* __restrict__ xlen,
                                                const int* __restrict__ ylen,
                                                float* __restrict__ out) {
    extern __shared__ char smem[];
    const int b = blockIdx.x, lane = threadIdx.x;
    const uint32_t base32 = (uint32_t)(uintptr_t)smem;   // LDS byte offset of base

    // ---- stage C (48KB) + sX into LDS (normal C; compiler-managed waits) ----
    {
        float4* s4 = (float4*)(smem + STG_OFF);
        const float4* g4 = (const float4*)C;
        #pragma unroll
        for (int k = 0; k < (S_DIM * A_DIM) / (4 * 64); ++k)
            s4[lane + 64 * k] = g4[lane + 64 * k];
        int* sx = (int*)(smem + SX_OFF);
        const int* xsb = xs + b * LX;
        #pragma unroll
        for (int k = 0; k < 4; ++k) sx[lane + 64 * k] = INF_ROW << 10;      // left pad
        #pragma unroll
        for (int k = 0; k < 8; ++k) sx[256 + lane + 64 * k] = xsb[lane + 64 * k] << 10;
        #pragma unroll
        for (int k = 0; k < 6; ++k) sx[768 + lane + 64 * k] = 0;            // right pad
    }
    __syncthreads();

    const int4 yv = *(const int4*)(ys + b * LY + lane * 4);
    const int y0 = yv.x, y1 = yv.y, y2 = yv.z, y3 = yv.w;

    // ---- build per-lane packed quads: packed[x][lane] = {T[x][y0..y3]} ----
    {
        const float* stg = (const float*)(smem + STG_OFF);
        char* pk = smem;
        const uint32_t woff = (uint32_t)(lane << 4);
        for (int x = 0; x < S_DIM; ++x) {
            const float* row = stg + A_DIM * x;
            f32x4 q;
            q.x = row[y0]; q.y = row[y1]; q.z = row[y2]; q.w = row[y3];
            *(f32x4*)(pk + ((uint32_t)x << 10) + woff) = q;
        }
        const float INF = __builtin_inff();
        f32x4 qi; qi.x = INF; qi.y = INF; qi.z = INF; qi.w = INF;
        *(f32x4*)(pk + ((uint32_t)INF_ROW << 10) + woff) = qi;
    }
    __syncthreads();

    const int xl = xlen[b] - 1;            // rows 1..xl (>=1)
    const int yl = ylen[b] - 1;            // answer column (>=1)
    const int lane_ans = (yl - 1) >> 2;
    const int tstar = ((xl + 3) >> 2) + lane_ans;  // phase where lane_ans covers row xl
    const int r_star = (xl + 3) & 3;               // row index within that phase
    const int N = tstar - 1;                       // full phases before the tail

    const uint32_t lane16b = base32 + (uint32_t)(lane << 4);
    // sX quad address for phase p: base32 + SX_OFF + 1024 + 16(p-1) - 16*lane
    const uint32_t xa1 = base32 + SX_OFF + 1024u - (uint32_t)(lane << 4);

    // ---- prologue: x-quads for phases 1..3, then cost quads for phase 1 ----
    i32x4 xq1 = ds_load4i(xa1);          // x for phase 1
    i32x4 xgA = ds_load4i(xa1 + 16u);    // x for phase 2 (used by phase 1)
    i32x4 xgB = ds_load4i(xa1 + 32u);    // x for phase 3 (used by phase 2)
    WAITK(0);
    f32x4 qA0, qA1, qA2, qA3, qB0, qB1, qB2, qB3;
    qA0 = ds_load4((uint32_t)xq1.x + lane16b);
    qA1 = ds_load4((uint32_t)xq1.y + lane16b);
    qA2 = ds_load4((uint32_t)xq1.z + lane16b);
    qA3 = ds_load4((uint32_t)xq1.w + lane16b);
    uint32_t xaddr = xa1 + 48u;          // next sX quad: phase 4

    float g0 = 0.f, g1 = 0.f, g2 = 0.f, g3 = 0.f;
    float h0 = 0.f, h1 = 0.f, h2 = 0.f, h3 = 0.f;

    // ---- main loop: N phases, buffers alternate A,B,A,... ----
    int pairs = N >> 1;
    if (N & 1) {
        PHASE_FULL(A, B);
        for (; pairs > 0; --pairs) { PHASE_FULL(B, A); PHASE_FULL(A, B); }
        TAIL(B);
    } else {
        for (; pairs > 0; --pairs) { PHASE_FULL(A, B); PHASE_FULL(B, A); }
        TAIL(A);
    }

    // ---- answer: D[xl][yl] = g + xl + yl ----
    if (lane == lane_ans) {
        int slot = (yl - 1) & 3;
        float r = (slot == 0) ? g0 : (slot == 1) ? g1 : (slot == 2) ? g2 : g3;
        out[b] = r + (float)(xl + yl);
    }
}

extern "C" void kernel_launch(void* const* d_in, const int* in_sizes, int n_in,
                              void* d_out, int out_size, void* d_ws, size_t ws_size,
                              hipStream_t stream) {
    const float* P  = (const float*)d_in[0];
    const int* xs   = (const int*)d_in[1];
    const int* ys   = (const int*)d_in[2];
    const int* xlen = (const int*)d_in[3];
    const int* ylen = (const int*)d_in[4];
    float* out = (float*)d_out;
    float* C = (float*)d_ws;  // S_DIM*A_DIM floats, holds -1 - softmax(P)

    (void)hipFuncSetAttribute((const void*)dp_kernel,
                              hipFuncAttributeMaxDynamicSharedMemorySize, LDS_BYTES);

    softmax_kernel<<<S_DIM, 64, 0, stream>>>(P, C);
    dp_kernel<<<B_DIM, 64, LDS_BYTES, stream>>>(C, xs, ys, xlen, ylen, out);
}